// Round 1
// baseline (297.219 us; speedup 1.0000x reference)
//
#include <hip/hip_runtime.h>
#include <hip/hip_bf16.h>
#include <cstdint>
#include <cstddef>

#define H_DIM 1024
#define I_DIM 512
#define E_NUM 32
#define SHARED_I_DIM 1024
#define TOPK 4
#define NGROUP 8
#define TOPKG 4

typedef __attribute__((ext_vector_type(8))) short bf16x8;
typedef __attribute__((ext_vector_type(4))) float f32x4;
typedef __attribute__((ext_vector_type(8))) unsigned short u16x8;

__device__ inline unsigned short f2bf(float f) {
    union { float f; unsigned int u; } v; v.f = f;
    unsigned int u = v.u;
    unsigned int r = (u + 0x7FFFu + ((u >> 16) & 1u)) >> 16;  // RNE
    return (unsigned short)r;
}

// ---------------- init: zero cnt + cnt2 ----------------
__global__ void init_kernel(int* cnt) {
    if (threadIdx.x < 64) cnt[threadIdx.x] = 0;
}

// ---------------- gating ----------------
__global__ void gate_kernel(const float* __restrict__ x, const float* __restrict__ gw,
                            const float* __restrict__ gb,
                            int* __restrict__ topk_e, float* __restrict__ topk_w,
                            int* __restrict__ cnt) {
    int t = blockIdx.x;
    int tid = threadIdx.x;
    int e = tid & 31, part = tid >> 5;            // 8 partial sums over H
    const float* wrow = gw + (size_t)e * H_DIM + part * 128;
    const float* xrow = x + (size_t)t * H_DIM + part * 128;
    float acc = 0.f;
#pragma unroll 8
    for (int h = 0; h < 128; h += 4) {
        float4 a = *(const float4*)(xrow + h);
        float4 b = *(const float4*)(wrow + h);
        acc += a.x * b.x + a.y * b.y + a.z * b.z + a.w * b.w;
    }
    __shared__ float partial[8][32];
    __shared__ float logits[32];
    partial[part][e] = acc;
    __syncthreads();
    if (tid < 32) {
        float l = 0.f;
#pragma unroll
        for (int p = 0; p < 8; p++) l += partial[p][tid];
        logits[tid] = l;
    }
    __syncthreads();
    if (tid == 0) {
        float scores[E_NUM], sfc[E_NUM];
        for (int i = 0; i < E_NUM; i++) {
            float s = 1.f / (1.f + expf(-logits[i]));
            scores[i] = s;
            sfc[i] = s + gb[i];
        }
        // group score = sum of top-2 in each group of 4
        float gs[NGROUP];
        for (int g = 0; g < NGROUP; g++) {
            float m1 = -1e30f, m2 = -1e30f;
            for (int j = 0; j < 4; j++) {
                float v = sfc[g * 4 + j];
                if (v > m1) { m2 = m1; m1 = v; }
                else if (v > m2) { m2 = v; }
            }
            gs[g] = m1 + m2;
        }
        // top-4 groups (ties -> lowest index, strict >)
        bool gsel[NGROUP] = {false, false, false, false, false, false, false, false};
        for (int r = 0; r < TOPKG; r++) {
            int best = -1; float bv = -1e30f;
            for (int g = 0; g < NGROUP; g++)
                if (!gsel[g] && gs[g] > bv) { bv = gs[g]; best = g; }
            gsel[best] = true;
        }
        float tmp[E_NUM];
        for (int i = 0; i < E_NUM; i++) tmp[i] = gsel[i >> 2] ? sfc[i] : 0.0f;
        int idx[TOPK]; float tw[TOPK]; float s = 0.f;
        for (int r = 0; r < TOPK; r++) {
            int best = -1; float bv = -1e30f;
            for (int i = 0; i < E_NUM; i++)
                if (tmp[i] > bv) { bv = tmp[i]; best = i; }
            idx[r] = best; tw[r] = scores[best]; s += tw[r];
            tmp[best] = -1e30f;
        }
        float inv = 1.f / (s + 1e-20f);
        for (int k = 0; k < TOPK; k++) {
            topk_e[t * TOPK + k] = idx[k];
            topk_w[t * TOPK + k] = tw[k] * inv;   // SCALE = 1
            atomicAdd(&cnt[idx[k]], 1);
        }
    }
}

// ---------------- scan: offsets ----------------
__global__ void scan_kernel(const int* __restrict__ cnt, int* __restrict__ off) {
    if (threadIdx.x == 0) {
        int a = 0;
        for (int e = 0; e < E_NUM; e++) { off[e] = a; a += cnt[e]; }
        off[E_NUM] = a;
    }
}

// ---------------- bin: token -> expert slots ----------------
__global__ void bin_kernel(const int* __restrict__ topk_e, const float* __restrict__ topk_w,
                           const int* __restrict__ off, int* __restrict__ cnt2,
                           int* __restrict__ slot_token, float* __restrict__ slot_w, int total) {
    int i = blockIdx.x * blockDim.x + threadIdx.x;
    if (i >= total) return;
    int e = topk_e[i];
    float w = topk_w[i];
    int pos = atomicAdd(&cnt2[e], 1);
    int slot = off[e] + pos;
    slot_token[slot] = i >> 2;
    slot_w[slot] = w;
}

// ---------------- generic 64x64 MFMA GEMM tile ----------------
// MODE 0: dst = bf16( silu(g)*u*w )   (DUAL must be true)
// MODE 1: dst(float) = acc            (plain store)
// MODE 2: atomicAdd(out[token], acc)  (routed scatter)
template <int MODE, bool DUAL, bool AF32, bool ROUTED, bool AGATHER>
__global__ __launch_bounds__(256) void gemm_kernel(
    const void* __restrict__ Asrc, const float* __restrict__ B1,
    const float* __restrict__ B2, size_t bstride,
    void* __restrict__ Dst, int ldD,
    const int* __restrict__ slot_token, const float* __restrict__ slot_w,
    const int* __restrict__ cnt, const int* __restrict__ off_arr, int K) {
    int itile = blockIdx.x, mtile = blockIdx.y;
    int e = ROUTED ? blockIdx.z : 0;
    int count = 0x40000000, base = 0;
    if (ROUTED) {
        count = cnt[e];
        base = off_arr[e];
        if (mtile * 64 >= count) return;
    }

    __shared__ __align__(16) unsigned short As[64][40];
    __shared__ __align__(16) unsigned short Bs1[64][40];
    __shared__ __align__(16) unsigned short Bs2[DUAL ? 64 : 1][40];

    int tid = threadIdx.x;
    int srow = tid >> 2, sseg = tid & 3;  // staging: 4 threads/row, 8 cols each

    int am = mtile * 64 + srow;
    int arow;
    if (AGATHER) {
        arow = (am < count) ? slot_token[base + am] : 0;
    } else if (ROUTED) {
        arow = base + am;
    } else {
        arow = am;
    }
    const float* Af = (const float*)Asrc + (size_t)arow * K;
    const unsigned short* Ab = (const unsigned short*)Asrc + (size_t)arow * K;

    int bn = itile * 64 + srow;
    const float* B1r = B1 + (size_t)e * bstride + (size_t)bn * K;
    const float* B2r = DUAL ? (B2 + (size_t)e * bstride + (size_t)bn * K) : nullptr;

    f32x4 acc1[2][2] = {};
    f32x4 acc2[2][2] = {};

    int lane = tid & 63, wid = tid >> 6;
    int wr = wid >> 1, wc = wid & 1;
    int frow = lane & 15, fk = (lane >> 4) * 8;

    for (int k0 = 0; k0 < K; k0 += 32) {
        __syncthreads();
        // ---- stage A ----
        if (AF32) {
            float4 a0 = *(const float4*)(Af + k0 + sseg * 8);
            float4 a1 = *(const float4*)(Af + k0 + sseg * 8 + 4);
            u16x8 s;
            s[0] = f2bf(a0.x); s[1] = f2bf(a0.y); s[2] = f2bf(a0.z); s[3] = f2bf(a0.w);
            s[4] = f2bf(a1.x); s[5] = f2bf(a1.y); s[6] = f2bf(a1.z); s[7] = f2bf(a1.w);
            *(u16x8*)(&As[srow][sseg * 8]) = s;
        } else {
            *(u16x8*)(&As[srow][sseg * 8]) = *(const u16x8*)(Ab + k0 + sseg * 8);
        }
        // ---- stage B1 ----
        {
            float4 b0 = *(const float4*)(B1r + k0 + sseg * 8);
            float4 b1 = *(const float4*)(B1r + k0 + sseg * 8 + 4);
            u16x8 s;
            s[0] = f2bf(b0.x); s[1] = f2bf(b0.y); s[2] = f2bf(b0.z); s[3] = f2bf(b0.w);
            s[4] = f2bf(b1.x); s[5] = f2bf(b1.y); s[6] = f2bf(b1.z); s[7] = f2bf(b1.w);
            *(u16x8*)(&Bs1[srow][sseg * 8]) = s;
        }
        if (DUAL) {
            float4 b0 = *(const float4*)(B2r + k0 + sseg * 8);
            float4 b1 = *(const float4*)(B2r + k0 + sseg * 8 + 4);
            u16x8 s;
            s[0] = f2bf(b0.x); s[1] = f2bf(b0.y); s[2] = f2bf(b0.z); s[3] = f2bf(b0.w);
            s[4] = f2bf(b1.x); s[5] = f2bf(b1.y); s[6] = f2bf(b1.z); s[7] = f2bf(b1.w);
            *(u16x8*)(&Bs2[srow][sseg * 8]) = s;
        }
        __syncthreads();
        // ---- fragments + MFMA ----
        bf16x8 a0 = *(const bf16x8*)(&As[wr * 32 + frow][fk]);
        bf16x8 a1 = *(const bf16x8*)(&As[wr * 32 + 16 + frow][fk]);
        bf16x8 b0 = *(const bf16x8*)(&Bs1[wc * 32 + frow][fk]);
        bf16x8 b1 = *(const bf16x8*)(&Bs1[wc * 32 + 16 + frow][fk]);
        acc1[0][0] = __builtin_amdgcn_mfma_f32_16x16x32_bf16(a0, b0, acc1[0][0], 0, 0, 0);
        acc1[0][1] = __builtin_amdgcn_mfma_f32_16x16x32_bf16(a0, b1, acc1[0][1], 0, 0, 0);
        acc1[1][0] = __builtin_amdgcn_mfma_f32_16x16x32_bf16(a1, b0, acc1[1][0], 0, 0, 0);
        acc1[1][1] = __builtin_amdgcn_mfma_f32_16x16x32_bf16(a1, b1, acc1[1][1], 0, 0, 0);
        if (DUAL) {
            bf16x8 c0 = *(const bf16x8*)(&Bs2[wc * 32 + frow][fk]);
            bf16x8 c1 = *(const bf16x8*)(&Bs2[wc * 32 + 16 + frow][fk]);
            acc2[0][0] = __builtin_amdgcn_mfma_f32_16x16x32_bf16(a0, c0, acc2[0][0], 0, 0, 0);
            acc2[0][1] = __builtin_amdgcn_mfma_f32_16x16x32_bf16(a0, c1, acc2[0][1], 0, 0, 0);
            acc2[1][0] = __builtin_amdgcn_mfma_f32_16x16x32_bf16(a1, c0, acc2[1][0], 0, 0, 0);
            acc2[1][1] = __builtin_amdgcn_mfma_f32_16x16x32_bf16(a1, c1, acc2[1][1], 0, 0, 0);
        }
    }

    // ---- epilogue ----
#pragma unroll
    for (int m = 0; m < 2; m++)
#pragma unroll
        for (int n = 0; n < 2; n++) {
            f32x4 vg = acc1[m][n];
            f32x4 vu = acc2[m][n];
#pragma unroll
            for (int j = 0; j < 4; j++) {
                int rloc = wr * 32 + m * 16 + (lane >> 4) * 4 + j;
                int cloc = wc * 32 + n * 16 + (lane & 15);
                int mrow = mtile * 64 + rloc;
                int col = itile * 64 + cloc;
                if constexpr (MODE == 0) {
                    if (!ROUTED || mrow < count) {
                        float w = ROUTED ? slot_w[base + mrow] : 1.0f;
                        float g = vg[j];
                        float a = (g / (1.f + __expf(-g))) * vu[j] * w;
                        ((unsigned short*)Dst)[(size_t)(base + mrow) * ldD + col] = f2bf(a);
                    }
                } else if constexpr (MODE == 1) {
                    ((float*)Dst)[(size_t)mrow * ldD + col] = vg[j];
                } else {
                    if (mrow < count) {
                        int t = slot_token[base + mrow];
                        atomicAdd(((float*)Dst) + (size_t)t * ldD + col, vg[j]);
                    }
                }
            }
        }
}

extern "C" void kernel_launch(void* const* d_in, const int* in_sizes, int n_in,
                              void* d_out, int out_size, void* d_ws, size_t ws_size,
                              hipStream_t stream) {
    const float* x = (const float*)d_in[0];
    const float* gw = (const float*)d_in[1];
    const float* gb = (const float*)d_in[2];
    const float* gate_proj = (const float*)d_in[3];
    const float* up_proj = (const float*)d_in[4];
    const float* down_proj = (const float*)d_in[5];
    const float* sgw = (const float*)d_in[6];
    const float* suw = (const float*)d_in[7];
    const float* sdw = (const float*)d_in[8];
    float* out = (float*)d_out;

    const int T = in_sizes[0] / H_DIM;       // 2048
    const int total_slots = T * TOPK;        // 8192

    char* ws = (char*)d_ws;
    int* cnt = (int*)ws;                     // 32
    int* cnt2 = cnt + 32;                    // 32
    int* off = cnt + 64;                     // 33 (fits in 64-slot pad)
    int* topk_e = cnt + 128;
    float* topk_w = (float*)(topk_e + total_slots);
    int* slot_token = (int*)(topk_w + total_slots);
    float* slot_w = (float*)(slot_token + total_slots);
    unsigned short* act_r = (unsigned short*)(slot_w + total_slots);      // (slots+64) x I
    unsigned short* act_s = act_r + (size_t)(total_slots + 64) * I_DIM;   // T x SHARED_I

    hipLaunchKernelGGL(init_kernel, dim3(1), dim3(64), 0, stream, cnt);
    hipLaunchKernelGGL(gate_kernel, dim3(T), dim3(256), 0, stream, x, gw, gb, topk_e, topk_w, cnt);
    hipLaunchKernelGGL(scan_kernel, dim3(1), dim3(1), 0, stream, cnt, off);
    hipLaunchKernelGGL(bin_kernel, dim3((total_slots + 255) / 256), dim3(256), 0, stream,
                       topk_e, topk_w, off, cnt2, slot_token, slot_w, total_slots);

    // routed stage 1: act = silu(x@gateT)*(x@upT)*w  -> bf16
    hipLaunchKernelGGL((gemm_kernel<0, true, true, true, true>),
                       dim3(I_DIM / 64, T / 64, E_NUM), dim3(256), 0, stream,
                       (const void*)x, gate_proj, up_proj, (size_t)I_DIM * H_DIM,
                       (void*)act_r, I_DIM, slot_token, slot_w, cnt, off, H_DIM);

    // shared stage 1
    hipLaunchKernelGGL((gemm_kernel<0, true, true, false, false>),
                       dim3(SHARED_I_DIM / 64, T / 64, 1), dim3(256), 0, stream,
                       (const void*)x, sgw, suw, (size_t)0,
                       (void*)act_s, SHARED_I_DIM, (const int*)nullptr, (const float*)nullptr,
                       (const int*)nullptr, (const int*)nullptr, H_DIM);

    // shared down: plain store (covers every (t,h) exactly once)
    hipLaunchKernelGGL((gemm_kernel<1, false, false, false, false>),
                       dim3(H_DIM / 64, T / 64, 1), dim3(256), 0, stream,
                       (const void*)act_s, sdw, (const float*)nullptr, (size_t)0,
                       (void*)out, H_DIM, (const int*)nullptr, (const float*)nullptr,
                       (const int*)nullptr, (const int*)nullptr, SHARED_I_DIM);

    // routed down: atomicAdd scatter onto shared result
    hipLaunchKernelGGL((gemm_kernel<2, false, false, true, false>),
                       dim3(H_DIM / 64, T / 64, E_NUM), dim3(256), 0, stream,
                       (const void*)act_r, down_proj, (const float*)nullptr, (size_t)H_DIM * I_DIM,
                       (void*)out, H_DIM, slot_token, slot_w, cnt, off, I_DIM);
}

// Round 2
// 282.409 us; speedup vs baseline: 1.0524x; 1.0524x over previous
//
#include <hip/hip_runtime.h>
#include <hip/hip_bf16.h>
#include <cstdint>
#include <cstddef>

#define H_DIM 1024
#define I_DIM 512
#define E_NUM 32
#define SHARED_I_DIM 1024
#define TOPK 4
#define NGROUP 8
#define TOPKG 4

typedef __attribute__((ext_vector_type(8))) short bf16x8;
typedef __attribute__((ext_vector_type(4))) float f32x4;
typedef __attribute__((ext_vector_type(8))) unsigned short u16x8;

__device__ inline unsigned short f2bf(float f) {
    __hip_bfloat16 h = __float2bfloat16(f);   // RNE, lowers to v_cvt_pk_bf16_f32
    return *reinterpret_cast<unsigned short*>(&h);
}

// LDS address (in shorts) for 64x64 bf16 tile, 16B-chunk XOR swizzle.
__device__ inline int laddr(int row, int chunk) {
    return row * 64 + (((chunk) ^ (row & 7)) << 3);
}

// ---------------- init: zero cnt + cnt2 ----------------
__global__ void init_kernel(int* cnt) {
    if (threadIdx.x < 64) cnt[threadIdx.x] = 0;
}

// ---------------- gating ----------------
__global__ void gate_kernel(const float* __restrict__ x, const float* __restrict__ gw,
                            const float* __restrict__ gb,
                            int* __restrict__ topk_e, float* __restrict__ topk_w,
                            int* __restrict__ cnt) {
    int t = blockIdx.x;
    int tid = threadIdx.x;
    int e = tid & 31, part = tid >> 5;            // 8 partial sums over H
    const float* wrow = gw + (size_t)e * H_DIM + part * 128;
    const float* xrow = x + (size_t)t * H_DIM + part * 128;
    float acc = 0.f;
#pragma unroll 8
    for (int h = 0; h < 128; h += 4) {
        float4 a = *(const float4*)(xrow + h);
        float4 b = *(const float4*)(wrow + h);
        acc += a.x * b.x + a.y * b.y + a.z * b.z + a.w * b.w;
    }
    __shared__ float partial[8][32];
    __shared__ float logits[32];
    partial[part][e] = acc;
    __syncthreads();
    if (tid < 32) {
        float l = 0.f;
#pragma unroll
        for (int p = 0; p < 8; p++) l += partial[p][tid];
        logits[tid] = l;
    }
    __syncthreads();
    if (tid == 0) {
        float scores[E_NUM], sfc[E_NUM];
        for (int i = 0; i < E_NUM; i++) {
            float s = 1.f / (1.f + expf(-logits[i]));
            scores[i] = s;
            sfc[i] = s + gb[i];
        }
        float gs[NGROUP];
        for (int g = 0; g < NGROUP; g++) {
            float m1 = -1e30f, m2 = -1e30f;
            for (int j = 0; j < 4; j++) {
                float v = sfc[g * 4 + j];
                if (v > m1) { m2 = m1; m1 = v; }
                else if (v > m2) { m2 = v; }
            }
            gs[g] = m1 + m2;
        }
        bool gsel[NGROUP] = {false, false, false, false, false, false, false, false};
        for (int r = 0; r < TOPKG; r++) {
            int best = -1; float bv = -1e30f;
            for (int g = 0; g < NGROUP; g++)
                if (!gsel[g] && gs[g] > bv) { bv = gs[g]; best = g; }
            gsel[best] = true;
        }
        float tmp[E_NUM];
        for (int i = 0; i < E_NUM; i++) tmp[i] = gsel[i >> 2] ? sfc[i] : 0.0f;
        int idx[TOPK]; float tw[TOPK]; float s = 0.f;
        for (int r = 0; r < TOPK; r++) {
            int best = -1; float bv = -1e30f;
            for (int i = 0; i < E_NUM; i++)
                if (tmp[i] > bv) { bv = tmp[i]; best = i; }
            idx[r] = best; tw[r] = scores[best]; s += tw[r];
            tmp[best] = -1e30f;
        }
        float inv = 1.f / (s + 1e-20f);
        for (int k = 0; k < TOPK; k++) {
            topk_e[t * TOPK + k] = idx[k];
            topk_w[t * TOPK + k] = tw[k] * inv;   // SCALE = 1
            atomicAdd(&cnt[idx[k]], 1);
        }
    }
}

// ---------------- scan: offsets ----------------
__global__ void scan_kernel(const int* __restrict__ cnt, int* __restrict__ off) {
    if (threadIdx.x == 0) {
        int a = 0;
        for (int e = 0; e < E_NUM; e++) { off[e] = a; a += cnt[e]; }
        off[E_NUM] = a;
    }
}

// ---------------- bin: token -> expert slots ----------------
__global__ void bin_kernel(const int* __restrict__ topk_e, const float* __restrict__ topk_w,
                           const int* __restrict__ off, int* __restrict__ cnt2,
                           int* __restrict__ slot_token, float* __restrict__ slot_w, int total) {
    int i = blockIdx.x * blockDim.x + threadIdx.x;
    if (i >= total) return;
    int e = topk_e[i];
    float w = topk_w[i];
    int pos = atomicAdd(&cnt2[e], 1);
    int slot = off[e] + pos;
    slot_token[slot] = i >> 2;
    slot_w[slot] = w;
}

// ---------------- stage helpers ----------------
__device__ inline void stage_f32(unsigned short* lds, int row, int chunk, const float* src) {
    float4 v0 = *(const float4*)(src);
    float4 v1 = *(const float4*)(src + 4);
    u16x8 s;
    s[0] = f2bf(v0.x); s[1] = f2bf(v0.y); s[2] = f2bf(v0.z); s[3] = f2bf(v0.w);
    s[4] = f2bf(v1.x); s[5] = f2bf(v1.y); s[6] = f2bf(v1.z); s[7] = f2bf(v1.w);
    *(u16x8*)(&lds[laddr(row, chunk)]) = s;
}
__device__ inline void stage_bf16(unsigned short* lds, int row, int chunk, const unsigned short* src) {
    *(u16x8*)(&lds[laddr(row, chunk)]) = *(const u16x8*)(src);
}

// ---------------- generic 64x64 MFMA GEMM tile, BK=64 ----------------
// MODE 0: dst = bf16( silu(g)*u*w )   (DUAL must be true)
// MODE 1: dst(float) = acc            (plain store)
// MODE 2: atomicAdd(out[token], acc)  (routed scatter)
template <int MODE, bool DUAL, bool AF32, bool ROUTED, bool AGATHER>
__global__ __launch_bounds__(256) void gemm_kernel(
    const void* __restrict__ Asrc, const float* __restrict__ B1,
    const float* __restrict__ B2, size_t bstride,
    void* __restrict__ Dst, int ldD,
    const int* __restrict__ slot_token, const float* __restrict__ slot_w,
    const int* __restrict__ cnt, const int* __restrict__ off_arr, int K) {
    int itile = blockIdx.x, mtile = blockIdx.y;
    int e = ROUTED ? blockIdx.z : 0;
    int count = 0x40000000, base = 0;
    if (ROUTED) {
        count = cnt[e];
        base = off_arr[e];
        if (mtile * 64 >= count) return;
    }

    __shared__ __align__(16) unsigned short As[64 * 64];
    __shared__ __align__(16) unsigned short Bs1[64 * 64];
    __shared__ __align__(16) unsigned short Bs2[DUAL ? 64 * 64 : 8];

    int tid = threadIdx.x;
    int srow = tid >> 3;      // 0..31 (two row passes: srow, srow+32)
    int schunk = tid & 7;     // 8-col chunk

    // A source rows for the two staging passes
    int am0 = mtile * 64 + srow;
    int am1 = am0 + 32;
    int arow0, arow1;
    if (AGATHER) {
        arow0 = (am0 < count) ? slot_token[base + am0] : 0;
        arow1 = (am1 < count) ? slot_token[base + am1] : 0;
    } else if (ROUTED) {
        arow0 = base + am0;
        arow1 = base + am1;
    } else {
        arow0 = am0;
        arow1 = am1;
    }
    const float* Af0 = (const float*)Asrc + (size_t)arow0 * K;
    const float* Af1 = (const float*)Asrc + (size_t)arow1 * K;
    const unsigned short* Ab0 = (const unsigned short*)Asrc + (size_t)arow0 * K;
    const unsigned short* Ab1 = (const unsigned short*)Asrc + (size_t)arow1 * K;

    int bn0 = itile * 64 + srow;
    const float* B1r0 = B1 + (size_t)e * bstride + (size_t)bn0 * K;
    const float* B1r1 = B1r0 + (size_t)32 * K;
    const float* B2r0 = DUAL ? (B2 + (size_t)e * bstride + (size_t)bn0 * K) : nullptr;
    const float* B2r1 = DUAL ? (B2r0 + (size_t)32 * K) : nullptr;

    f32x4 acc1[2][2] = {};
    f32x4 acc2[2][2] = {};

    int lane = tid & 63, wid = tid >> 6;
    int wr = wid >> 1, wc = wid & 1;
    int frow = lane & 15, fchunk = lane >> 4;   // 0..3

    int coff = schunk * 8;
    for (int k0 = 0; k0 < K; k0 += 64) {
        __syncthreads();
        if (AF32) {
            stage_f32(As, srow, schunk, Af0 + k0 + coff);
            stage_f32(As, srow + 32, schunk, Af1 + k0 + coff);
        } else {
            stage_bf16(As, srow, schunk, Ab0 + k0 + coff);
            stage_bf16(As, srow + 32, schunk, Ab1 + k0 + coff);
        }
        stage_f32(Bs1, srow, schunk, B1r0 + k0 + coff);
        stage_f32(Bs1, srow + 32, schunk, B1r1 + k0 + coff);
        if (DUAL) {
            stage_f32(Bs2, srow, schunk, B2r0 + k0 + coff);
            stage_f32(Bs2, srow + 32, schunk, B2r1 + k0 + coff);
        }
        __syncthreads();
#pragma unroll
        for (int kk = 0; kk < 2; kk++) {
            int cb = fchunk + kk * 4;
            bf16x8 a0 = *(const bf16x8*)(&As[laddr(wr * 32 + frow, cb)]);
            bf16x8 a1 = *(const bf16x8*)(&As[laddr(wr * 32 + 16 + frow, cb)]);
            bf16x8 b0 = *(const bf16x8*)(&Bs1[laddr(wc * 32 + frow, cb)]);
            bf16x8 b1 = *(const bf16x8*)(&Bs1[laddr(wc * 32 + 16 + frow, cb)]);
            acc1[0][0] = __builtin_amdgcn_mfma_f32_16x16x32_bf16(a0, b0, acc1[0][0], 0, 0, 0);
            acc1[0][1] = __builtin_amdgcn_mfma_f32_16x16x32_bf16(a0, b1, acc1[0][1], 0, 0, 0);
            acc1[1][0] = __builtin_amdgcn_mfma_f32_16x16x32_bf16(a1, b0, acc1[1][0], 0, 0, 0);
            acc1[1][1] = __builtin_amdgcn_mfma_f32_16x16x32_bf16(a1, b1, acc1[1][1], 0, 0, 0);
            if (DUAL) {
                bf16x8 c0 = *(const bf16x8*)(&Bs2[laddr(wc * 32 + frow, cb)]);
                bf16x8 c1 = *(const bf16x8*)(&Bs2[laddr(wc * 32 + 16 + frow, cb)]);
                acc2[0][0] = __builtin_amdgcn_mfma_f32_16x16x32_bf16(a0, c0, acc2[0][0], 0, 0, 0);
                acc2[0][1] = __builtin_amdgcn_mfma_f32_16x16x32_bf16(a0, c1, acc2[0][1], 0, 0, 0);
                acc2[1][0] = __builtin_amdgcn_mfma_f32_16x16x32_bf16(a1, c0, acc2[1][0], 0, 0, 0);
                acc2[1][1] = __builtin_amdgcn_mfma_f32_16x16x32_bf16(a1, c1, acc2[1][1], 0, 0, 0);
            }
        }
    }

    // ---- epilogue ----
#pragma unroll
    for (int m = 0; m < 2; m++)
#pragma unroll
        for (int n = 0; n < 2; n++) {
            f32x4 vg = acc1[m][n];
            f32x4 vu = acc2[m][n];
#pragma unroll
            for (int j = 0; j < 4; j++) {
                int rloc = wr * 32 + m * 16 + (lane >> 4) * 4 + j;
                int cloc = wc * 32 + n * 16 + (lane & 15);
                int mrow = mtile * 64 + rloc;
                int col = itile * 64 + cloc;
                if constexpr (MODE == 0) {
                    if (!ROUTED || mrow < count) {
                        float w = ROUTED ? slot_w[base + mrow] : 1.0f;
                        float g = vg[j];
                        float a = (g / (1.f + __expf(-g))) * vu[j] * w;
                        ((unsigned short*)Dst)[(size_t)(base + mrow) * ldD + col] = f2bf(a);
                    }
                } else if constexpr (MODE == 1) {
                    ((float*)Dst)[(size_t)mrow * ldD + col] = vg[j];
                } else {
                    if (mrow < count) {
                        int t = slot_token[base + mrow];
                        atomicAdd(((float*)Dst) + (size_t)t * ldD + col, vg[j]);
                    }
                }
            }
        }
}

extern "C" void kernel_launch(void* const* d_in, const int* in_sizes, int n_in,
                              void* d_out, int out_size, void* d_ws, size_t ws_size,
                              hipStream_t stream) {
    const float* x = (const float*)d_in[0];
    const float* gw = (const float*)d_in[1];
    const float* gb = (const float*)d_in[2];
    const float* gate_proj = (const float*)d_in[3];
    const float* up_proj = (const float*)d_in[4];
    const float* down_proj = (const float*)d_in[5];
    const float* sgw = (const float*)d_in[6];
    const float* suw = (const float*)d_in[7];
    const float* sdw = (const float*)d_in[8];
    float* out = (float*)d_out;

    const int T = in_sizes[0] / H_DIM;       // 2048
    const int total_slots = T * TOPK;        // 8192

    char* ws = (char*)d_ws;
    int* cnt = (int*)ws;                     // 32
    int* cnt2 = cnt + 32;                    // 32
    int* off = cnt + 64;                     // 33 (fits in 64-slot pad)
    int* topk_e = cnt + 128;
    float* topk_w = (float*)(topk_e + total_slots);
    int* slot_token = (int*)(topk_w + total_slots);
    float* slot_w = (float*)(slot_token + total_slots);
    unsigned short* act_r = (unsigned short*)(slot_w + total_slots);      // (slots+64) x I
    unsigned short* act_s = act_r + (size_t)(total_slots + 64) * I_DIM;   // T x SHARED_I

    hipLaunchKernelGGL(init_kernel, dim3(1), dim3(64), 0, stream, cnt);
    hipLaunchKernelGGL(gate_kernel, dim3(T), dim3(256), 0, stream, x, gw, gb, topk_e, topk_w, cnt);
    hipLaunchKernelGGL(scan_kernel, dim3(1), dim3(1), 0, stream, cnt, off);
    hipLaunchKernelGGL(bin_kernel, dim3((total_slots + 255) / 256), dim3(256), 0, stream,
                       topk_e, topk_w, off, cnt2, slot_token, slot_w, total_slots);

    // routed stage 1: act = silu(x@gateT)*(x@upT)*w  -> bf16
    hipLaunchKernelGGL((gemm_kernel<0, true, true, true, true>),
                       dim3(I_DIM / 64, T / 64, E_NUM), dim3(256), 0, stream,
                       (const void*)x, gate_proj, up_proj, (size_t)I_DIM * H_DIM,
                       (void*)act_r, I_DIM, slot_token, slot_w, cnt, off, H_DIM);

    // shared stage 1
    hipLaunchKernelGGL((gemm_kernel<0, true, true, false, false>),
                       dim3(SHARED_I_DIM / 64, T / 64, 1), dim3(256), 0, stream,
                       (const void*)x, sgw, suw, (size_t)0,
                       (void*)act_s, SHARED_I_DIM, (const int*)nullptr, (const float*)nullptr,
                       (const int*)nullptr, (const int*)nullptr, H_DIM);

    // shared down: plain store (covers every (t,h) exactly once)
    hipLaunchKernelGGL((gemm_kernel<1, false, false, false, false>),
                       dim3(H_DIM / 64, T / 64, 1), dim3(256), 0, stream,
                       (const void*)act_s, sdw, (const float*)nullptr, (size_t)0,
                       (void*)out, H_DIM, (const int*)nullptr, (const float*)nullptr,
                       (const int*)nullptr, (const int*)nullptr, SHARED_I_DIM);

    // routed down: atomicAdd scatter onto shared result
    hipLaunchKernelGGL((gemm_kernel<2, false, false, true, false>),
                       dim3(H_DIM / 64, T / 64, E_NUM), dim3(256), 0, stream,
                       (const void*)act_r, down_proj, (const float*)nullptr, (size_t)H_DIM * I_DIM,
                       (void*)out, H_DIM, slot_token, slot_w, cnt, off, I_DIM);
}